// Round 10
// baseline (226.043 us; speedup 1.0000x reference)
//
#include <hip/hip_runtime.h>
#include <hip/hip_cooperative_groups.h>

namespace cg = cooperative_groups;

#define NPTS  131072
#define NB    1024
#define NI    256
#define NA    32
#define RR    8
#define ND    28
#define NCELL 343
#define CAP   768
#define NCHUNKS 3
#define CHUNK 256
#define GRID  256

typedef _Float16 half8v __attribute__((ext_vector_type(8)));
typedef float    f32x4  __attribute__((ext_vector_type(4)));

struct SmemG { alignas(16) _Float16 Bs[8 * 32 * 32]; float Ds[4][16][33]; };
struct SmemS { int sc[NCELL]; int sbase[NCELL]; };
struct SmemR { float wtot[4]; float wred[4][5]; };
union  SmemU { SmemG g; SmemS s; SmemR r; };

// ---------------------------------------------------------------------------
// shared device helpers
// ---------------------------------------------------------------------------
__device__ __forceinline__ void cell_coords(const float* __restrict__ ip, int p,
                                            int& ix, int& iy, int& iz) {
  float cx = fminf(fmaxf(ip[p * 3 + 0] * 7.f, 0.f), 7.f);
  float cy = fminf(fmaxf(ip[p * 3 + 1] * 7.f, 0.f), 7.f);
  float cz = fminf(fmaxf(ip[p * 3 + 2] * 7.f, 0.f), 7.f);
  ix = (int)floorf(cx); ix = ix > 6 ? 6 : ix;
  iy = (int)floorf(cy); iy = iy > 6 ? 6 : iy;
  iz = (int)floorf(cz); iz = iz > 6 ? 6 : iz;
}

// ---------------------------------------------------------------------------
// cooperative mega-kernel
// ---------------------------------------------------------------------------
__global__ __launch_bounds__(256) void mega_kernel(
    const float* __restrict__ atoms, _Float16* __restrict__ atomsH,
    f32x4* __restrict__ zbuf, int* __restrict__ cnt, int* __restrict__ perm,
    const float* __restrict__ queries, const float* __restrict__ intrs_pts,
    const float* __restrict__ rays_d, const int* __restrict__ scatter_idx,
    float* __restrict__ sigma_d, float* __restrict__ rgb_d,
    const float* __restrict__ intersections, float* __restrict__ out) {
  __shared__ SmemU smem;
  cg::grid_group grid = cg::this_grid();
  int t = threadIdx.x;

  // ---------------- phase 0: transpose atoms + zero sigma/rgb + zero cnt ----
  for (int idx = blockIdx.x * 256 + t; idx < 512 * 1024; idx += GRID * 256) {
    int vox = idx >> 10;
    int d = (idx >> 5) & 31;
    int a = idx & 31;
    float v = 0.f;
    if (d < ND) v = atoms[(a * 512 + vox) * ND + d];
    atomsH[idx] = (_Float16)v;
    if (idx < NB * NI) { f32x4 z = {0.f, 0.f, 0.f, 0.f}; zbuf[idx] = z; }
    if (idx < NCELL) cnt[idx] = 0;
  }
  __threadfence();
  grid.sync();

  // ---------------- phase 1: two-level scatter (all 256 blocks, 512 pts) ---
  {
    for (int c = t; c < NCELL; c += 256) smem.s.sc[c] = 0;
    __syncthreads();
    int mycell[2], myrank[2], myp[2];
#pragma unroll
    for (int u = 0; u < 2; u++) {
      int p = blockIdx.x * 512 + u * 256 + t;
      int ix, iy, iz;
      cell_coords(intrs_pts, p, ix, iy, iz);
      int cell = (ix * 7 + iy) * 7 + iz;
      mycell[u] = cell;
      myp[u] = p;
      myrank[u] = atomicAdd(&smem.s.sc[cell], 1);
    }
    __syncthreads();
    for (int c = t; c < NCELL; c += 256) {
      int n = smem.s.sc[c];
      smem.s.sbase[c] = n ? atomicAdd(&cnt[c], n) : 0;
    }
    __syncthreads();
#pragma unroll
    for (int u = 0; u < 2; u++)
      perm[mycell[u] * CAP + smem.s.sbase[mycell[u]] + myrank[u]] = myp[u];
  }
  __threadfence();
  grid.sync();

  // ---------------- phase 2: cell GEMM -------------------------------------
  int lane = t & 63, w = t >> 6;
  int n0 = lane & 15, kg = lane >> 4;
  for (int item = blockIdx.x; item < NCELL * NCHUNKS; item += GRID) {
    int cell = item / NCHUNKS;
    int chunk = item - cell * NCHUNKS;
    int n = cnt[cell];
    int s0 = chunk * CHUNK;
    if (s0 < n) {                     // block-uniform guard
      int e0 = min(n, s0 + CHUNK);
      const int* pcell = perm + cell * CAP;
      int cx = cell / 49, cy = (cell / 7) % 7, cz = cell % 7;

      // stage B: 8 corners x 32 d x 32 a fp16 = 16 KB, a-chunk XOR-swizzled
#pragma unroll
      for (int u = 0; u < 4; u++) {
        int g = (t + u * 256) << 3;
        int c = g >> 10;
        int rem = g & 1023;
        int d = rem >> 5;
        int kgs = (rem >> 3) & 3;
        int vox = ((cx + (c >> 2)) * RR + cy + ((c >> 1) & 1)) * RR + cz + (c & 1);
        const _Float16* src = atomsH + vox * 1024 + d * 32 + (kgs << 3);
        int swz = kgs ^ ((d >> 1) & 3);
        _Float16* dst = smem.g.Bs + c * 1024 + d * 32 + (swz << 3);
        *(half8v*)dst = *(const half8v*)src;
      }
      __syncthreads();

      half8v Bf[8][2];
#pragma unroll
      for (int s = 0; s < 8; s++)
#pragma unroll
        for (int dt = 0; dt < 2; dt++) {
          int nn = n0 + 16 * dt;
          int swz = kg ^ ((nn >> 1) & 3);
          Bf[s][dt] = *(const half8v*)(smem.g.Bs + (s * 32 + nn) * 32 + (swz << 3));
        }

      for (int tile = 0; tile < 4; tile++) {
        int pbase = s0 + w * 64 + tile * 16;   // wave-uniform
        if (pbase >= e0) break;
        int pidx = pbase + n0;
        bool valid = pidx < e0;
        int p = valid ? pcell[pidx] : 0;

        float cxv = fminf(fmaxf(intrs_pts[p * 3 + 0] * 7.f, 0.f), 7.f);
        float cyv = fminf(fmaxf(intrs_pts[p * 3 + 1] * 7.f, 0.f), 7.f);
        float czv = fminf(fmaxf(intrs_pts[p * 3 + 2] * 7.f, 0.f), 7.f);
        float fx = cxv - (float)cx;
        float fy = cyv - (float)cy;
        float fz = czv - (float)cz;
        float vm = valid ? 1.f : 0.f;

        float wgt[8];
#pragma unroll
        for (int s = 0; s < 8; s++)
          wgt[s] = vm * ((s & 4) ? fx : 1.f - fx) * ((s & 2) ? fy : 1.f - fy) *
                   ((s & 1) ? fz : 1.f - fz);

        f32x4 q0 = *(const f32x4*)(queries + p * NA + kg * 8);
        f32x4 q1 = *(const f32x4*)(queries + p * NA + kg * 8 + 4);
        half8v qh;
        qh[0] = (_Float16)q0[0]; qh[1] = (_Float16)q0[1];
        qh[2] = (_Float16)q0[2]; qh[3] = (_Float16)q0[3];
        qh[4] = (_Float16)q1[0]; qh[5] = (_Float16)q1[1];
        qh[6] = (_Float16)q1[2]; qh[7] = (_Float16)q1[3];

        f32x4 acc0 = {0.f, 0.f, 0.f, 0.f};
        f32x4 acc1 = {0.f, 0.f, 0.f, 0.f};
#pragma unroll
        for (int s = 0; s < 8; s++) {
          _Float16 wh = (_Float16)wgt[s];
          half8v ws8 = {wh, wh, wh, wh, wh, wh, wh, wh};
          half8v af = qh * ws8;
          acc0 = __builtin_amdgcn_mfma_f32_16x16x32_f16(af, Bf[s][0], acc0, 0, 0, 0);
          acc1 = __builtin_amdgcn_mfma_f32_16x16x32_f16(af, Bf[s][1], acc1, 0, 0, 0);
        }

        // Ds[w] is wave-private; within-wave LDS RAW needs no barrier
#pragma unroll
        for (int r = 0; r < 4; r++) {
          smem.g.Ds[w][kg * 4 + r][n0]      = acc0[r];
          smem.g.Ds[w][kg * 4 + r][n0 + 16] = acc1[r];
        }

        int m16 = n0, o = kg;   // 16 points x 4 outputs (rgb0,rgb1,rgb2,sigma)
        int pe = pbase + m16;
        if (pe < e0) {
          int p2 = pcell[pe];
          int sidx = scatter_idx[p2];
          if (o == 3) {
            sigma_d[sidx] = smem.g.Ds[w][m16][27];
          } else {
            int b = sidx >> 8;
            float rxv = rays_d[b * 3 + 0], ryv = rays_d[b * 3 + 1],
                  rzv = rays_d[b * 3 + 2];
            float inv = rsqrtf(rxv * rxv + ryv * ryv + rzv * rzv);
            float X = rxv * inv, Y = ryv * inv, Z = rzv * inv;
            float shb[9];
            shb[0] = 0.28209479177387814f;
            shb[1] = -0.4886025119029199f * Y;
            shb[2] = 0.4886025119029199f * Z;
            shb[3] = -0.4886025119029199f * X;
            shb[4] = 1.0925484305920792f * X * Y;
            shb[5] = -1.0925484305920792f * Y * Z;
            shb[6] = 0.31539156525252005f * (2.f * Z * Z - X * X - Y * Y);
            shb[7] = -1.0925484305920792f * X * Z;
            shb[8] = 0.5462742152960396f * (X * X - Y * Y);
            float sum = 0.f;
#pragma unroll
            for (int sh = 0; sh < 9; sh++)
              sum += shb[sh] * smem.g.Ds[w][m16][o * 9 + sh];
            rgb_d[(size_t)sidx * 3 + o] = sum;
          }
        }
      }
    }
    __syncthreads();   // protect Bs/Ds reuse across items (block-uniform)
  }
  __threadfence();
  grid.sync();

  // ---------------- phase 3: per-ray integration ---------------------------
  int wid = t >> 6;
  for (int b = blockIdx.x; b < NB; b += GRID) {
    int i = t;
    float t0 = intersections[b * (NI + 1) + i];
    float t1 = intersections[b * (NI + 1) + i + 1];
    float rxv = rays_d[b * 3 + 0], ryv = rays_d[b * 3 + 1], rzv = rays_d[b * 3 + 2];
    float nrm = sqrtf(rxv * rxv + ryv * ryv + rzv * rzv);
    float dist = (t1 - t0) * nrm;
    float mid = 0.5f * (t0 + t1);

    float sg = fmaxf(sigma_d[b * NI + i], 0.f);
    float alpha = 1.f - expf(-sg * dist);
    out[3072 + b * NI + i] = alpha;

    float x = 1.f - alpha + 1e-10f;

    float v = x;
#pragma unroll
    for (int off = 1; off < 64; off <<= 1) {
      float tv = __shfl_up(v, off, 64);
      if (lane >= off) v *= tv;
    }
    if (lane == 63) smem.r.wtot[wid] = v;
    __syncthreads();
    float pre = 1.f;
    for (int w2 = 0; w2 < wid; w2++) pre *= smem.r.wtot[w2];
    float vprev = __shfl_up(v, 1, 64);
    float trans = (lane == 0) ? pre : pre * vprev;
    float al = alpha * trans;

    float r0 = rgb_d[(size_t)(b * NI + i) * 3 + 0];
    float r1 = rgb_d[(size_t)(b * NI + i) * 3 + 1];
    float r2 = rgb_d[(size_t)(b * NI + i) * 3 + 2];
    float g0 = 1.f / (1.f + expf(-r0));
    float g1 = 1.f / (1.f + expf(-r1));
    float g2 = 1.f / (1.f + expf(-r2));

    float v0 = al, v1 = al * mid, v2 = al * g0, v3 = al * g1, v4 = al * g2;
#pragma unroll
    for (int off = 1; off < 64; off <<= 1) {
      v0 += __shfl_xor(v0, off, 64);
      v1 += __shfl_xor(v1, off, 64);
      v2 += __shfl_xor(v2, off, 64);
      v3 += __shfl_xor(v3, off, 64);
      v4 += __shfl_xor(v4, off, 64);
    }
    if (lane == 0) {
      smem.r.wred[wid][0] = v0; smem.r.wred[wid][1] = v1; smem.r.wred[wid][2] = v2;
      smem.r.wred[wid][3] = v3; smem.r.wred[wid][4] = v4;
    }
    __syncthreads();
    if (i == 0) {
      float a0 = 0.f, a1 = 0.f, a2 = 0.f, a3 = 0.f, a4 = 0.f;
#pragma unroll
      for (int w2 = 0; w2 < 4; w2++) {
        a0 += smem.r.wred[w2][0]; a1 += smem.r.wred[w2][1]; a2 += smem.r.wred[w2][2];
        a3 += smem.r.wred[w2][3]; a4 += smem.r.wred[w2][4];
      }
      float white = 1.f - a0;
      out[b * 3 + 0] = a2 + white;
      out[b * 3 + 1] = a3 + white;
      out[b * 3 + 2] = a4 + white;
      out[3072 + NB * NI + b] = a1;
    }
    __syncthreads();   // protect wtot/wred reuse across rays
  }
}

// ---------------------------------------------------------------------------
// fallback pipeline (R8, proven 36 µs) — used only if cooperative launch fails
// ---------------------------------------------------------------------------
__global__ __launch_bounds__(256) void init_transpose(const float* __restrict__ atoms,
                                                      _Float16* __restrict__ atomsH,
                                                      f32x4* __restrict__ zbuf,
                                                      int* __restrict__ cnt) {
  int idx = blockIdx.x * 256 + threadIdx.x;
  int vox = idx >> 10;
  int d = (idx >> 5) & 31;
  int a = idx & 31;
  float v = 0.f;
  if (d < ND) v = atoms[(a * 512 + vox) * ND + d];
  atomsH[idx] = (_Float16)v;
  if (idx < NB * NI) { f32x4 z = {0.f, 0.f, 0.f, 0.f}; zbuf[idx] = z; }
  if (idx < NCELL) cnt[idx] = 0;
}

__global__ __launch_bounds__(256) void scatter_kernel(const float* __restrict__ ip,
                                                      int* __restrict__ cnt,
                                                      int* __restrict__ perm) {
  __shared__ int sc[NCELL];
  __shared__ int sbase[NCELL];
  for (int c = threadIdx.x; c < NCELL; c += 256) sc[c] = 0;
  __syncthreads();
  int mycell[4], myrank[4], myp[4];
#pragma unroll
  for (int u = 0; u < 4; u++) {
    int p = blockIdx.x * 1024 + u * 256 + threadIdx.x;
    int ix, iy, iz;
    cell_coords(ip, p, ix, iy, iz);
    int cell = (ix * 7 + iy) * 7 + iz;
    mycell[u] = cell;
    myp[u] = p;
    myrank[u] = atomicAdd(&sc[cell], 1);
  }
  __syncthreads();
  for (int c = threadIdx.x; c < NCELL; c += 256) {
    int n = sc[c];
    sbase[c] = n ? atomicAdd(&cnt[c], n) : 0;
  }
  __syncthreads();
#pragma unroll
  for (int u = 0; u < 4; u++)
    perm[mycell[u] * CAP + sbase[mycell[u]] + myrank[u]] = myp[u];
}

__global__ __launch_bounds__(256) void gemm_points(
    const int* __restrict__ cnt, const int* __restrict__ perm,
    const float* __restrict__ queries, const float* __restrict__ intrs_pts,
    const float* __restrict__ rays_d, const int* __restrict__ scatter_idx,
    const _Float16* __restrict__ atomsH,
    float* __restrict__ sigma_d, float* __restrict__ rgb_d) {
  int cell = blockIdx.x / NCHUNKS;
  int chunk = blockIdx.x - cell * NCHUNKS;
  int n = cnt[cell];
  int s0 = chunk * CHUNK;
  if (s0 >= n) return;
  int e0 = min(n, s0 + CHUNK);
  const int* pcell = perm + cell * CAP;
  int cx = cell / 49, cy = (cell / 7) % 7, cz = cell % 7;

  __shared__ _Float16 Bs[8 * 32 * 32];
  __shared__ float Ds[4][16][33];
  int t = threadIdx.x;
#pragma unroll
  for (int u = 0; u < 4; u++) {
    int g = (t + u * 256) << 3;
    int c = g >> 10;
    int rem = g & 1023;
    int d = rem >> 5;
    int kgs = (rem >> 3) & 3;
    int vox = ((cx + (c >> 2)) * RR + cy + ((c >> 1) & 1)) * RR + cz + (c & 1);
    const _Float16* src = atomsH + vox * 1024 + d * 32 + (kgs << 3);
    int swz = kgs ^ ((d >> 1) & 3);
    _Float16* dst = Bs + c * 1024 + d * 32 + (swz << 3);
    *(half8v*)dst = *(const half8v*)src;
  }
  __syncthreads();

  int lane = t & 63, w = t >> 6;
  int n0 = lane & 15, kg = lane >> 4;
  half8v Bf[8][2];
#pragma unroll
  for (int s = 0; s < 8; s++)
#pragma unroll
    for (int dt = 0; dt < 2; dt++) {
      int nn = n0 + 16 * dt;
      int swz = kg ^ ((nn >> 1) & 3);
      Bf[s][dt] = *(const half8v*)(Bs + (s * 32 + nn) * 32 + (swz << 3));
    }

  for (int tile = 0; tile < 4; tile++) {
    int pbase = s0 + w * 64 + tile * 16;
    if (pbase >= e0) break;
    int pidx = pbase + n0;
    bool valid = pidx < e0;
    int p = valid ? pcell[pidx] : 0;

    float cxv = fminf(fmaxf(intrs_pts[p * 3 + 0] * 7.f, 0.f), 7.f);
    float cyv = fminf(fmaxf(intrs_pts[p * 3 + 1] * 7.f, 0.f), 7.f);
    float czv = fminf(fmaxf(intrs_pts[p * 3 + 2] * 7.f, 0.f), 7.f);
    float fx = cxv - (float)cx;
    float fy = cyv - (float)cy;
    float fz = czv - (float)cz;
    float vm = valid ? 1.f : 0.f;

    float wgt[8];
#pragma unroll
    for (int s = 0; s < 8; s++)
      wgt[s] = vm * ((s & 4) ? fx : 1.f - fx) * ((s & 2) ? fy : 1.f - fy) *
               ((s & 1) ? fz : 1.f - fz);

    f32x4 q0 = *(const f32x4*)(queries + p * NA + kg * 8);
    f32x4 q1 = *(const f32x4*)(queries + p * NA + kg * 8 + 4);
    half8v qh;
    qh[0] = (_Float16)q0[0]; qh[1] = (_Float16)q0[1];
    qh[2] = (_Float16)q0[2]; qh[3] = (_Float16)q0[3];
    qh[4] = (_Float16)q1[0]; qh[5] = (_Float16)q1[1];
    qh[6] = (_Float16)q1[2]; qh[7] = (_Float16)q1[3];

    f32x4 acc0 = {0.f, 0.f, 0.f, 0.f};
    f32x4 acc1 = {0.f, 0.f, 0.f, 0.f};
#pragma unroll
    for (int s = 0; s < 8; s++) {
      _Float16 wh = (_Float16)wgt[s];
      half8v ws8 = {wh, wh, wh, wh, wh, wh, wh, wh};
      half8v af = qh * ws8;
      acc0 = __builtin_amdgcn_mfma_f32_16x16x32_f16(af, Bf[s][0], acc0, 0, 0, 0);
      acc1 = __builtin_amdgcn_mfma_f32_16x16x32_f16(af, Bf[s][1], acc1, 0, 0, 0);
    }
#pragma unroll
    for (int r = 0; r < 4; r++) {
      Ds[w][kg * 4 + r][n0]      = acc0[r];
      Ds[w][kg * 4 + r][n0 + 16] = acc1[r];
    }
    int m16 = n0, o = kg;
    int pe = pbase + m16;
    if (pe < e0) {
      int p2 = pcell[pe];
      int sidx = scatter_idx[p2];
      if (o == 3) {
        sigma_d[sidx] = Ds[w][m16][27];
      } else {
        int b = sidx >> 8;
        float rxv = rays_d[b * 3 + 0], ryv = rays_d[b * 3 + 1], rzv = rays_d[b * 3 + 2];
        float inv = rsqrtf(rxv * rxv + ryv * ryv + rzv * rzv);
        float X = rxv * inv, Y = ryv * inv, Z = rzv * inv;
        float shb[9];
        shb[0] = 0.28209479177387814f;
        shb[1] = -0.4886025119029199f * Y;
        shb[2] = 0.4886025119029199f * Z;
        shb[3] = -0.4886025119029199f * X;
        shb[4] = 1.0925484305920792f * X * Y;
        shb[5] = -1.0925484305920792f * Y * Z;
        shb[6] = 0.31539156525252005f * (2.f * Z * Z - X * X - Y * Y);
        shb[7] = -1.0925484305920792f * X * Z;
        shb[8] = 0.5462742152960396f * (X * X - Y * Y);
        float sum = 0.f;
#pragma unroll
        for (int sh = 0; sh < 9; sh++) sum += shb[sh] * Ds[w][m16][o * 9 + sh];
        rgb_d[(size_t)sidx * 3 + o] = sum;
      }
    }
  }
}

__global__ __launch_bounds__(256) void ray_kernel(
    const float* __restrict__ intersections, const float* __restrict__ rays_d,
    const float* __restrict__ sigma_d, const float* __restrict__ rgb_d,
    float* __restrict__ out) {
  int b = blockIdx.x;
  int i = threadIdx.x;
  int wid = i >> 6;
  int lane = i & 63;

  float t0 = intersections[b * (NI + 1) + i];
  float t1 = intersections[b * (NI + 1) + i + 1];
  float rxv = rays_d[b * 3 + 0], ryv = rays_d[b * 3 + 1], rzv = rays_d[b * 3 + 2];
  float nrm = sqrtf(rxv * rxv + ryv * ryv + rzv * rzv);
  float dist = (t1 - t0) * nrm;
  float mid = 0.5f * (t0 + t1);

  float sg = fmaxf(sigma_d[b * NI + i], 0.f);
  float alpha = 1.f - expf(-sg * dist);
  out[3072 + b * NI + i] = alpha;

  float x = 1.f - alpha + 1e-10f;
  float v = x;
#pragma unroll
  for (int off = 1; off < 64; off <<= 1) {
    float tv = __shfl_up(v, off, 64);
    if (lane >= off) v *= tv;
  }
  __shared__ float wtot[4];
  if (lane == 63) wtot[wid] = v;
  __syncthreads();
  float pre = 1.f;
  for (int w2 = 0; w2 < wid; w2++) pre *= wtot[w2];
  float vprev = __shfl_up(v, 1, 64);
  float trans = (lane == 0) ? pre : pre * vprev;
  float al = alpha * trans;

  float r0 = rgb_d[(size_t)(b * NI + i) * 3 + 0];
  float r1 = rgb_d[(size_t)(b * NI + i) * 3 + 1];
  float r2 = rgb_d[(size_t)(b * NI + i) * 3 + 2];
  float g0 = 1.f / (1.f + expf(-r0));
  float g1 = 1.f / (1.f + expf(-r1));
  float g2 = 1.f / (1.f + expf(-r2));

  float v0 = al, v1 = al * mid, v2 = al * g0, v3 = al * g1, v4 = al * g2;
#pragma unroll
  for (int off = 1; off < 64; off <<= 1) {
    v0 += __shfl_xor(v0, off, 64);
    v1 += __shfl_xor(v1, off, 64);
    v2 += __shfl_xor(v2, off, 64);
    v3 += __shfl_xor(v3, off, 64);
    v4 += __shfl_xor(v4, off, 64);
  }
  __shared__ float wred[4][5];
  if (lane == 0) {
    wred[wid][0] = v0; wred[wid][1] = v1; wred[wid][2] = v2;
    wred[wid][3] = v3; wred[wid][4] = v4;
  }
  __syncthreads();
  if (i == 0) {
    float a0 = 0.f, a1 = 0.f, a2 = 0.f, a3 = 0.f, a4 = 0.f;
#pragma unroll
    for (int w2 = 0; w2 < 4; w2++) {
      a0 += wred[w2][0]; a1 += wred[w2][1]; a2 += wred[w2][2];
      a3 += wred[w2][3]; a4 += wred[w2][4];
    }
    float white = 1.f - a0;
    out[b * 3 + 0] = a2 + white;
    out[b * 3 + 1] = a3 + white;
    out[b * 3 + 2] = a4 + white;
    out[3072 + NB * NI + b] = a1;
  }
}

extern "C" void kernel_launch(void* const* d_in, const int* in_sizes, int n_in,
                              void* d_out, int out_size, void* d_ws, size_t ws_size,
                              hipStream_t stream) {
  const float* rays_d        = (const float*)d_in[0];
  const float* queries       = (const float*)d_in[1];
  const float* intrs_pts     = (const float*)d_in[2];
  const float* intersections = (const float*)d_in[3];
  const float* atoms         = (const float*)d_in[4];
  const int*   scatter_idx   = (const int*)d_in[5];
  float* out = (float*)d_out;

  float*    sigma_d = (float*)d_ws;                       // 262144 f   (1 MB)
  float*    rgb_d   = sigma_d + NB * NI;                  // 786432 f   (3 MB)
  _Float16* atomsH  = (_Float16*)(rgb_d + (size_t)NB * NI * 3);  // 524288 h (1 MB)
  int*      perm    = (int*)(atomsH + 512 * 1024);        // NCELL*CAP i (~1 MB)
  int*      cnt     = perm + NCELL * CAP;                 // 343
  f32x4*    zbuf    = (f32x4*)d_ws;

  void* args[] = {(void*)&atoms, (void*)&atomsH, (void*)&zbuf, (void*)&cnt,
                  (void*)&perm, (void*)&queries, (void*)&intrs_pts,
                  (void*)&rays_d, (void*)&scatter_idx, (void*)&sigma_d,
                  (void*)&rgb_d, (void*)&intersections, (void*)&out};
  hipError_t rc = hipLaunchCooperativeKernel((const void*)mega_kernel, dim3(GRID),
                                             dim3(256), args, 0, stream);
  if (rc != hipSuccess) {
    // fallback: proven 4-kernel pipeline
    init_transpose<<<2048, 256, 0, stream>>>(atoms, atomsH, zbuf, cnt);
    scatter_kernel<<<128, 256, 0, stream>>>(intrs_pts, cnt, perm);
    gemm_points<<<NCELL * NCHUNKS, 256, 0, stream>>>(cnt, perm, queries, intrs_pts,
                                                     rays_d, scatter_idx, atomsH,
                                                     sigma_d, rgb_d);
    ray_kernel<<<NB, 256, 0, stream>>>(intersections, rays_d, sigma_d, rgb_d, out);
  }
}

// Round 11
// 41.428 us; speedup vs baseline: 5.4563x; 5.4563x over previous
//
#include <hip/hip_runtime.h>

#define NPTS  131072
#define NB    1024
#define NI    256
#define NA    32
#define RR    8
#define ND    28
#define NCELL 343
#define CAP   768
#define NCHUNKS 12
#define CHUNK 64

typedef _Float16 half8v __attribute__((ext_vector_type(8)));
typedef float    f32x4  __attribute__((ext_vector_type(4)));

__device__ __forceinline__ void cell_coords(const float* __restrict__ ip, int p,
                                            int& ix, int& iy, int& iz) {
  float cx = fminf(fmaxf(ip[p * 3 + 0] * 7.f, 0.f), 7.f);
  float cy = fminf(fmaxf(ip[p * 3 + 1] * 7.f, 0.f), 7.f);
  float cz = fminf(fmaxf(ip[p * 3 + 2] * 7.f, 0.f), 7.f);
  ix = (int)floorf(cx); ix = ix > 6 ? 6 : ix;
  iy = (int)floorf(cy); iy = iy > 6 ? 6 : iy;
  iz = (int)floorf(cz); iz = iz > 6 ? 6 : iz;
}

// fused: atoms[a][vox][d] -> atomsH[vox][d][a] fp16  +  zero sigma/rgb  +  zero cnt
__global__ __launch_bounds__(256) void init_transpose(const float* __restrict__ atoms,
                                                      _Float16* __restrict__ atomsH,
                                                      f32x4* __restrict__ zbuf,
                                                      int* __restrict__ cnt) {
  int idx = blockIdx.x * 256 + threadIdx.x;  // 0 .. 524287
  int vox = idx >> 10;
  int d = (idx >> 5) & 31;
  int a = idx & 31;
  float v = 0.f;
  if (d < ND) v = atoms[(a * 512 + vox) * ND + d];
  atomsH[idx] = (_Float16)v;
  if (idx < NB * NI) { f32x4 z = {0.f, 0.f, 0.f, 0.f}; zbuf[idx] = z; }
  if (idx < NCELL) cnt[idx] = 0;
}

// two-level scatter into fixed-capacity cell segments; cnt[cell] ends as count
__global__ __launch_bounds__(256) void scatter_kernel(const float* __restrict__ ip,
                                                      int* __restrict__ cnt,
                                                      int* __restrict__ perm) {
  __shared__ int sc[NCELL];
  __shared__ int sbase[NCELL];
  for (int c = threadIdx.x; c < NCELL; c += 256) sc[c] = 0;
  __syncthreads();
  int mycell[4], myrank[4], myp[4];
#pragma unroll
  for (int u = 0; u < 4; u++) {
    int p = blockIdx.x * 1024 + u * 256 + threadIdx.x;
    int ix, iy, iz;
    cell_coords(ip, p, ix, iy, iz);
    int cell = (ix * 7 + iy) * 7 + iz;
    mycell[u] = cell;
    myp[u] = p;
    myrank[u] = atomicAdd(&sc[cell], 1);
  }
  __syncthreads();
  for (int c = threadIdx.x; c < NCELL; c += 256) {
    int n = sc[c];
    sbase[c] = n ? atomicAdd(&cnt[c], n) : 0;
  }
  __syncthreads();
#pragma unroll
  for (int u = 0; u < 4; u++)
    perm[mycell[u] * CAP + sbase[mycell[u]] + myrank[u]] = myp[u];
}

// one block per (cell, chunk of 64 points); 4 waves, each wave ONE tile of 16 pts.
// B fragments loaded straight from atomsH (L1/L2-resident) — no LDS staging.
__global__ __launch_bounds__(256) void gemm_points(
    const int* __restrict__ cnt, const int* __restrict__ perm,
    const float* __restrict__ queries, const float* __restrict__ intrs_pts,
    const float* __restrict__ rays_d, const int* __restrict__ scatter_idx,
    const _Float16* __restrict__ atomsH,
    float* __restrict__ sigma_d, float* __restrict__ rgb_d) {
  int cell = blockIdx.x / NCHUNKS;
  int chunk = blockIdx.x - cell * NCHUNKS;
  int n = cnt[cell];
  int s0 = chunk * CHUNK;
  if (s0 >= n) return;
  int e0 = min(n, s0 + CHUNK);
  const int* pcell = perm + cell * CAP;
  int cx = cell / 49, cy = (cell / 7) % 7, cz = cell % 7;

  __shared__ float Ds[4][16][33];

  int t = threadIdx.x;
  int lane = t & 63, w = t >> 6;
  int n0 = lane & 15, kg = lane >> 4;

  int pbase = s0 + w * 16;          // wave-uniform
  if (pbase >= e0) return;          // whole wave idle -> exit

  int pidx = pbase + n0;
  bool valid = pidx < e0;
  int p = valid ? pcell[pidx] : 0;

  float cxv = fminf(fmaxf(intrs_pts[p * 3 + 0] * 7.f, 0.f), 7.f);
  float cyv = fminf(fmaxf(intrs_pts[p * 3 + 1] * 7.f, 0.f), 7.f);
  float czv = fminf(fmaxf(intrs_pts[p * 3 + 2] * 7.f, 0.f), 7.f);
  float fx = cxv - (float)cx;
  float fy = cyv - (float)cy;
  float fz = czv - (float)cz;
  float vm = valid ? 1.f : 0.f;

  float wgt[8];
#pragma unroll
  for (int s = 0; s < 8; s++)
    wgt[s] = vm * ((s & 4) ? fx : 1.f - fx) * ((s & 2) ? fy : 1.f - fy) *
             ((s & 1) ? fz : 1.f - fz);

  f32x4 q0 = *(const f32x4*)(queries + p * NA + kg * 8);
  f32x4 q1 = *(const f32x4*)(queries + p * NA + kg * 8 + 4);
  half8v qh;
  qh[0] = (_Float16)q0[0]; qh[1] = (_Float16)q0[1];
  qh[2] = (_Float16)q0[2]; qh[3] = (_Float16)q0[3];
  qh[4] = (_Float16)q1[0]; qh[5] = (_Float16)q1[1];
  qh[6] = (_Float16)q1[2]; qh[7] = (_Float16)q1[3];

  f32x4 acc0 = {0.f, 0.f, 0.f, 0.f};
  f32x4 acc1 = {0.f, 0.f, 0.f, 0.f};
#pragma unroll
  for (int s = 0; s < 8; s++) {
    int vox = ((cx + (s >> 2)) * RR + cy + ((s >> 1) & 1)) * RR + cz + (s & 1);
    const _Float16* bp = atomsH + vox * 1024 + kg * 8;
    half8v b0 = *(const half8v*)(bp + n0 * 32);          // coalesced 1 KB/wave
    half8v b1 = *(const half8v*)(bp + (n0 + 16) * 32);
    _Float16 wh = (_Float16)wgt[s];
    half8v ws8 = {wh, wh, wh, wh, wh, wh, wh, wh};
    half8v af = qh * ws8;
    acc0 = __builtin_amdgcn_mfma_f32_16x16x32_f16(af, b0, acc0, 0, 0, 0);
    acc1 = __builtin_amdgcn_mfma_f32_16x16x32_f16(af, b1, acc1, 0, 0, 0);
  }

  // epilogue: Ds[w] is wave-private; within-wave LDS RAW needs no barrier
#pragma unroll
  for (int r = 0; r < 4; r++) {
    Ds[w][kg * 4 + r][n0]      = acc0[r];
    Ds[w][kg * 4 + r][n0 + 16] = acc1[r];
  }

  int m16 = n0, o = kg;   // 16 points x 4 outputs (rgb0,rgb1,rgb2,sigma)
  int pe = pbase + m16;
  if (pe < e0) {
    int p2 = pcell[pe];
    int sidx = scatter_idx[p2];
    if (o == 3) {
      sigma_d[sidx] = Ds[w][m16][27];
    } else {
      int b = sidx >> 8;
      float rxv = rays_d[b * 3 + 0], ryv = rays_d[b * 3 + 1], rzv = rays_d[b * 3 + 2];
      float inv = rsqrtf(rxv * rxv + ryv * ryv + rzv * rzv);
      float X = rxv * inv, Y = ryv * inv, Z = rzv * inv;
      float shb[9];
      shb[0] = 0.28209479177387814f;
      shb[1] = -0.4886025119029199f * Y;
      shb[2] = 0.4886025119029199f * Z;
      shb[3] = -0.4886025119029199f * X;
      shb[4] = 1.0925484305920792f * X * Y;
      shb[5] = -1.0925484305920792f * Y * Z;
      shb[6] = 0.31539156525252005f * (2.f * Z * Z - X * X - Y * Y);
      shb[7] = -1.0925484305920792f * X * Z;
      shb[8] = 0.5462742152960396f * (X * X - Y * Y);
      float sum = 0.f;
#pragma unroll
      for (int sh = 0; sh < 9; sh++) sum += shb[sh] * Ds[w][m16][o * 9 + sh];
      rgb_d[(size_t)sidx * 3 + o] = sum;
    }
  }
}

// one 256-thread block per ray; wave-level scan
__global__ __launch_bounds__(256) void ray_kernel(
    const float* __restrict__ intersections, const float* __restrict__ rays_d,
    const float* __restrict__ sigma_d, const float* __restrict__ rgb_d,
    float* __restrict__ out) {
  int b = blockIdx.x;
  int i = threadIdx.x;
  int wid = i >> 6;
  int lane = i & 63;

  float t0 = intersections[b * (NI + 1) + i];
  float t1 = intersections[b * (NI + 1) + i + 1];
  float rxv = rays_d[b * 3 + 0], ryv = rays_d[b * 3 + 1], rzv = rays_d[b * 3 + 2];
  float nrm = sqrtf(rxv * rxv + ryv * ryv + rzv * rzv);
  float dist = (t1 - t0) * nrm;
  float mid = 0.5f * (t0 + t1);

  float sg = fmaxf(sigma_d[b * NI + i], 0.f);
  float alpha = 1.f - expf(-sg * dist);
  out[3072 + b * NI + i] = alpha;

  float x = 1.f - alpha + 1e-10f;
  float v = x;
#pragma unroll
  for (int off = 1; off < 64; off <<= 1) {
    float tv = __shfl_up(v, off, 64);
    if (lane >= off) v *= tv;
  }
  __shared__ float wtot[4];
  if (lane == 63) wtot[wid] = v;
  __syncthreads();
  float pre = 1.f;
  for (int w2 = 0; w2 < wid; w2++) pre *= wtot[w2];
  float vprev = __shfl_up(v, 1, 64);
  float trans = (lane == 0) ? pre : pre * vprev;
  float al = alpha * trans;

  float r0 = rgb_d[(size_t)(b * NI + i) * 3 + 0];
  float r1 = rgb_d[(size_t)(b * NI + i) * 3 + 1];
  float r2 = rgb_d[(size_t)(b * NI + i) * 3 + 2];
  float g0 = 1.f / (1.f + expf(-r0));
  float g1 = 1.f / (1.f + expf(-r1));
  float g2 = 1.f / (1.f + expf(-r2));

  float v0 = al, v1 = al * mid, v2 = al * g0, v3 = al * g1, v4 = al * g2;
#pragma unroll
  for (int off = 1; off < 64; off <<= 1) {
    v0 += __shfl_xor(v0, off, 64);
    v1 += __shfl_xor(v1, off, 64);
    v2 += __shfl_xor(v2, off, 64);
    v3 += __shfl_xor(v3, off, 64);
    v4 += __shfl_xor(v4, off, 64);
  }
  __shared__ float wred[4][5];
  if (lane == 0) {
    wred[wid][0] = v0; wred[wid][1] = v1; wred[wid][2] = v2;
    wred[wid][3] = v3; wred[wid][4] = v4;
  }
  __syncthreads();
  if (i == 0) {
    float a0 = 0.f, a1 = 0.f, a2 = 0.f, a3 = 0.f, a4 = 0.f;
#pragma unroll
    for (int w2 = 0; w2 < 4; w2++) {
      a0 += wred[w2][0]; a1 += wred[w2][1]; a2 += wred[w2][2];
      a3 += wred[w2][3]; a4 += wred[w2][4];
    }
    float white = 1.f - a0;
    out[b * 3 + 0] = a2 + white;
    out[b * 3 + 1] = a3 + white;
    out[b * 3 + 2] = a4 + white;
    out[3072 + NB * NI + b] = a1;
  }
}

extern "C" void kernel_launch(void* const* d_in, const int* in_sizes, int n_in,
                              void* d_out, int out_size, void* d_ws, size_t ws_size,
                              hipStream_t stream) {
  const float* rays_d        = (const float*)d_in[0];
  const float* queries       = (const float*)d_in[1];
  const float* intrs_pts     = (const float*)d_in[2];
  const float* intersections = (const float*)d_in[3];
  const float* atoms         = (const float*)d_in[4];
  const int*   scatter_idx   = (const int*)d_in[5];
  float* out = (float*)d_out;

  float*    sigma_d = (float*)d_ws;                       // 262144 f   (1 MB)
  float*    rgb_d   = sigma_d + NB * NI;                  // 786432 f   (3 MB)
  _Float16* atomsH  = (_Float16*)(rgb_d + (size_t)NB * NI * 3);  // 524288 h (1 MB)
  int*      perm    = (int*)(atomsH + 512 * 1024);        // NCELL*CAP i (~1 MB)
  int*      cnt     = perm + NCELL * CAP;                 // 343

  init_transpose<<<2048, 256, 0, stream>>>(atoms, atomsH, (f32x4*)d_ws, cnt);
  scatter_kernel<<<128, 256, 0, stream>>>(intrs_pts, cnt, perm);
  gemm_points<<<NCELL * NCHUNKS, 256, 0, stream>>>(cnt, perm, queries, intrs_pts,
                                                   rays_d, scatter_idx, atomsH,
                                                   sigma_d, rgb_d);
  ray_kernel<<<NB, 256, 0, stream>>>(intersections, rays_d, sigma_d, rgb_d, out);
}

// Round 12
// 35.471 us; speedup vs baseline: 6.3726x; 1.1679x over previous
//
#include <hip/hip_runtime.h>

#define NPTS  131072
#define NB    1024
#define NI    256
#define NA    32
#define RR    8
#define ND    28
#define NCELL 343
#define CAP   768
#define NCHUNKS 12
#define CHUNK 64

typedef _Float16 half8v __attribute__((ext_vector_type(8)));
typedef float    f32x4  __attribute__((ext_vector_type(4)));

__device__ __forceinline__ void cell_coords(const float* __restrict__ ip, int p,
                                            int& ix, int& iy, int& iz) {
  float cx = fminf(fmaxf(ip[p * 3 + 0] * 7.f, 0.f), 7.f);
  float cy = fminf(fmaxf(ip[p * 3 + 1] * 7.f, 0.f), 7.f);
  float cz = fminf(fmaxf(ip[p * 3 + 2] * 7.f, 0.f), 7.f);
  ix = (int)floorf(cx); ix = ix > 6 ? 6 : ix;
  iy = (int)floorf(cy); iy = iy > 6 ? 6 : iy;
  iz = (int)floorf(cz); iz = iz > 6 ? 6 : iz;
}

// fused: atoms[a][vox][d] -> atomsH[vox][d][a] fp16  +  zero sigma/rgb  +  zero cnt
__global__ __launch_bounds__(256) void init_transpose(const float* __restrict__ atoms,
                                                      _Float16* __restrict__ atomsH,
                                                      f32x4* __restrict__ zbuf,
                                                      int* __restrict__ cnt) {
  int idx = blockIdx.x * 256 + threadIdx.x;  // 0 .. 524287
  int vox = idx >> 10;
  int d = (idx >> 5) & 31;
  int a = idx & 31;
  float v = 0.f;
  if (d < ND) v = atoms[(a * 512 + vox) * ND + d];
  atomsH[idx] = (_Float16)v;
  if (idx < NB * NI) { f32x4 z = {0.f, 0.f, 0.f, 0.f}; zbuf[idx] = z; }
  if (idx < NCELL) cnt[idx] = 0;
}

// two-level scatter into fixed-capacity cell segments; cnt[cell] ends as count
__global__ __launch_bounds__(256) void scatter_kernel(const float* __restrict__ ip,
                                                      int* __restrict__ cnt,
                                                      int* __restrict__ perm) {
  __shared__ int sc[NCELL];
  __shared__ int sbase[NCELL];
  for (int c = threadIdx.x; c < NCELL; c += 256) sc[c] = 0;
  __syncthreads();
  int mycell[4], myrank[4], myp[4];
#pragma unroll
  for (int u = 0; u < 4; u++) {
    int p = blockIdx.x * 1024 + u * 256 + threadIdx.x;
    int ix, iy, iz;
    cell_coords(ip, p, ix, iy, iz);
    int cell = (ix * 7 + iy) * 7 + iz;
    mycell[u] = cell;
    myp[u] = p;
    myrank[u] = atomicAdd(&sc[cell], 1);
  }
  __syncthreads();
  for (int c = threadIdx.x; c < NCELL; c += 256) {
    int n = sc[c];
    sbase[c] = n ? atomicAdd(&cnt[c], n) : 0;
  }
  __syncthreads();
#pragma unroll
  for (int u = 0; u < 4; u++)
    perm[mycell[u] * CAP + sbase[mycell[u]] + myrank[u]] = myp[u];
}

// one block per (cell, chunk of 64 points); 4 waves; LDS-staged B; 1 tile/wave
__global__ __launch_bounds__(256) void gemm_points(
    const int* __restrict__ cnt, const int* __restrict__ perm,
    const float* __restrict__ queries, const float* __restrict__ intrs_pts,
    const float* __restrict__ rays_d, const int* __restrict__ scatter_idx,
    const _Float16* __restrict__ atomsH,
    float* __restrict__ sigma_d, float* __restrict__ rgb_d) {
  int cell = blockIdx.x / NCHUNKS;
  int chunk = blockIdx.x - cell * NCHUNKS;
  int n = cnt[cell];
  int s0 = chunk * CHUNK;
  if (s0 >= n) return;                    // block-uniform early out
  int e0 = min(n, s0 + CHUNK);
  const int* pcell = perm + cell * CAP;
  int cx = cell / 49, cy = (cell / 7) % 7, cz = cell % 7;

  __shared__ _Float16 Bs[8 * 32 * 32];    // [corner][d][a], a-chunk XOR-swizzled
  __shared__ float Ds[4][16][33];

  int t = threadIdx.x;
  // stage B: 8 corners x 32 d x 32 a fp16 = 16 KB (all threads participate)
#pragma unroll
  for (int u = 0; u < 4; u++) {
    int g = (t + u * 256) << 3;
    int c = g >> 10;
    int rem = g & 1023;
    int d = rem >> 5;
    int kgs = (rem >> 3) & 3;
    int vox = ((cx + (c >> 2)) * RR + cy + ((c >> 1) & 1)) * RR + cz + (c & 1);
    const _Float16* src = atomsH + vox * 1024 + d * 32 + (kgs << 3);
    int swz = kgs ^ ((d >> 1) & 3);
    _Float16* dst = Bs + c * 1024 + d * 32 + (swz << 3);
    *(half8v*)dst = *(const half8v*)src;
  }
  __syncthreads();

  int lane = t & 63, w = t >> 6;
  int n0 = lane & 15, kg = lane >> 4;

  int pbase = s0 + w * 16;                // wave-uniform; each wave = one tile
  if (pbase >= e0) return;                // safe: after the barrier

  int pidx = pbase + n0;
  bool valid = pidx < e0;
  int p = valid ? pcell[pidx] : 0;

  float cxv = fminf(fmaxf(intrs_pts[p * 3 + 0] * 7.f, 0.f), 7.f);
  float cyv = fminf(fmaxf(intrs_pts[p * 3 + 1] * 7.f, 0.f), 7.f);
  float czv = fminf(fmaxf(intrs_pts[p * 3 + 2] * 7.f, 0.f), 7.f);
  float fx = cxv - (float)cx;
  float fy = cyv - (float)cy;
  float fz = czv - (float)cz;
  float vm = valid ? 1.f : 0.f;

  float wgt[8];
#pragma unroll
  for (int s = 0; s < 8; s++)
    wgt[s] = vm * ((s & 4) ? fx : 1.f - fx) * ((s & 2) ? fy : 1.f - fy) *
             ((s & 1) ? fz : 1.f - fz);

  f32x4 q0 = *(const f32x4*)(queries + p * NA + kg * 8);
  f32x4 q1 = *(const f32x4*)(queries + p * NA + kg * 8 + 4);
  half8v qh;
  qh[0] = (_Float16)q0[0]; qh[1] = (_Float16)q0[1];
  qh[2] = (_Float16)q0[2]; qh[3] = (_Float16)q0[3];
  qh[4] = (_Float16)q1[0]; qh[5] = (_Float16)q1[1];
  qh[6] = (_Float16)q1[2]; qh[7] = (_Float16)q1[3];

  f32x4 acc0 = {0.f, 0.f, 0.f, 0.f};
  f32x4 acc1 = {0.f, 0.f, 0.f, 0.f};
#pragma unroll
  for (int s = 0; s < 8; s++) {
    int swz0 = kg ^ ((n0 >> 1) & 3);
    int swz1 = kg ^ (((n0 + 16) >> 1) & 3);
    half8v b0 = *(const half8v*)(Bs + (s * 32 + n0) * 32 + (swz0 << 3));
    half8v b1 = *(const half8v*)(Bs + (s * 32 + n0 + 16) * 32 + (swz1 << 3));
    _Float16 wh = (_Float16)wgt[s];
    half8v ws8 = {wh, wh, wh, wh, wh, wh, wh, wh};
    half8v af = qh * ws8;
    acc0 = __builtin_amdgcn_mfma_f32_16x16x32_f16(af, b0, acc0, 0, 0, 0);
    acc1 = __builtin_amdgcn_mfma_f32_16x16x32_f16(af, b1, acc1, 0, 0, 0);
  }

  // epilogue: Ds[w] is wave-private; within-wave LDS RAW needs no barrier
#pragma unroll
  for (int r = 0; r < 4; r++) {
    Ds[w][kg * 4 + r][n0]      = acc0[r];
    Ds[w][kg * 4 + r][n0 + 16] = acc1[r];
  }

  int m16 = n0, o = kg;   // 16 points x 4 outputs (rgb0,rgb1,rgb2,sigma)
  int pe = pbase + m16;
  if (pe < e0) {
    int p2 = pcell[pe];
    int sidx = scatter_idx[p2];
    if (o == 3) {
      sigma_d[sidx] = Ds[w][m16][27];
    } else {
      int b = sidx >> 8;
      float rxv = rays_d[b * 3 + 0], ryv = rays_d[b * 3 + 1], rzv = rays_d[b * 3 + 2];
      float inv = rsqrtf(rxv * rxv + ryv * ryv + rzv * rzv);
      float X = rxv * inv, Y = ryv * inv, Z = rzv * inv;
      float shb[9];
      shb[0] = 0.28209479177387814f;
      shb[1] = -0.4886025119029199f * Y;
      shb[2] = 0.4886025119029199f * Z;
      shb[3] = -0.4886025119029199f * X;
      shb[4] = 1.0925484305920792f * X * Y;
      shb[5] = -1.0925484305920792f * Y * Z;
      shb[6] = 0.31539156525252005f * (2.f * Z * Z - X * X - Y * Y);
      shb[7] = -1.0925484305920792f * X * Z;
      shb[8] = 0.5462742152960396f * (X * X - Y * Y);
      float sum = 0.f;
#pragma unroll
      for (int sh = 0; sh < 9; sh++) sum += shb[sh] * Ds[w][m16][o * 9 + sh];
      rgb_d[(size_t)sidx * 3 + o] = sum;
    }
  }
}

// one 256-thread block per ray; wave-level scan
__global__ __launch_bounds__(256) void ray_kernel(
    const float* __restrict__ intersections, const float* __restrict__ rays_d,
    const float* __restrict__ sigma_d, const float* __restrict__ rgb_d,
    float* __restrict__ out) {
  int b = blockIdx.x;
  int i = threadIdx.x;
  int wid = i >> 6;
  int lane = i & 63;

  float t0 = intersections[b * (NI + 1) + i];
  float t1 = intersections[b * (NI + 1) + i + 1];
  float rxv = rays_d[b * 3 + 0], ryv = rays_d[b * 3 + 1], rzv = rays_d[b * 3 + 2];
  float nrm = sqrtf(rxv * rxv + ryv * ryv + rzv * rzv);
  float dist = (t1 - t0) * nrm;
  float mid = 0.5f * (t0 + t1);

  float sg = fmaxf(sigma_d[b * NI + i], 0.f);
  float alpha = 1.f - expf(-sg * dist);
  out[3072 + b * NI + i] = alpha;

  float x = 1.f - alpha + 1e-10f;
  float v = x;
#pragma unroll
  for (int off = 1; off < 64; off <<= 1) {
    float tv = __shfl_up(v, off, 64);
    if (lane >= off) v *= tv;
  }
  __shared__ float wtot[4];
  if (lane == 63) wtot[wid] = v;
  __syncthreads();
  float pre = 1.f;
  for (int w2 = 0; w2 < wid; w2++) pre *= wtot[w2];
  float vprev = __shfl_up(v, 1, 64);
  float trans = (lane == 0) ? pre : pre * vprev;
  float al = alpha * trans;

  float r0 = rgb_d[(size_t)(b * NI + i) * 3 + 0];
  float r1 = rgb_d[(size_t)(b * NI + i) * 3 + 1];
  float r2 = rgb_d[(size_t)(b * NI + i) * 3 + 2];
  float g0 = 1.f / (1.f + expf(-r0));
  float g1 = 1.f / (1.f + expf(-r1));
  float g2 = 1.f / (1.f + expf(-r2));

  float v0 = al, v1 = al * mid, v2 = al * g0, v3 = al * g1, v4 = al * g2;
#pragma unroll
  for (int off = 1; off < 64; off <<= 1) {
    v0 += __shfl_xor(v0, off, 64);
    v1 += __shfl_xor(v1, off, 64);
    v2 += __shfl_xor(v2, off, 64);
    v3 += __shfl_xor(v3, off, 64);
    v4 += __shfl_xor(v4, off, 64);
  }
  __shared__ float wred[4][5];
  if (lane == 0) {
    wred[wid][0] = v0; wred[wid][1] = v1; wred[wid][2] = v2;
    wred[wid][3] = v3; wred[wid][4] = v4;
  }
  __syncthreads();
  if (i == 0) {
    float a0 = 0.f, a1 = 0.f, a2 = 0.f, a3 = 0.f, a4 = 0.f;
#pragma unroll
    for (int w2 = 0; w2 < 4; w2++) {
      a0 += wred[w2][0]; a1 += wred[w2][1]; a2 += wred[w2][2];
      a3 += wred[w2][3]; a4 += wred[w2][4];
    }
    float white = 1.f - a0;
    out[b * 3 + 0] = a2 + white;
    out[b * 3 + 1] = a3 + white;
    out[b * 3 + 2] = a4 + white;
    out[3072 + NB * NI + b] = a1;
  }
}

extern "C" void kernel_launch(void* const* d_in, const int* in_sizes, int n_in,
                              void* d_out, int out_size, void* d_ws, size_t ws_size,
                              hipStream_t stream) {
  const float* rays_d        = (const float*)d_in[0];
  const float* queries       = (const float*)d_in[1];
  const float* intrs_pts     = (const float*)d_in[2];
  const float* intersections = (const float*)d_in[3];
  const float* atoms         = (const float*)d_in[4];
  const int*   scatter_idx   = (const int*)d_in[5];
  float* out = (float*)d_out;

  float*    sigma_d = (float*)d_ws;                       // 262144 f   (1 MB)
  float*    rgb_d   = sigma_d + NB * NI;                  // 786432 f   (3 MB)
  _Float16* atomsH  = (_Float16*)(rgb_d + (size_t)NB * NI * 3);  // 524288 h (1 MB)
  int*      perm    = (int*)(atomsH + 512 * 1024);        // NCELL*CAP i (~1 MB)
  int*      cnt     = perm + NCELL * CAP;                 // 343

  init_transpose<<<2048, 256, 0, stream>>>(atoms, atomsH, (f32x4*)d_ws, cnt);
  scatter_kernel<<<128, 256, 0, stream>>>(intrs_pts, cnt, perm);
  gemm_points<<<NCELL * NCHUNKS, 256, 0, stream>>>(cnt, perm, queries, intrs_pts,
                                                   rays_d, scatter_idx, atomsH,
                                                   sigma_d, rgb_d);
  ray_kernel<<<NB, 256, 0, stream>>>(intersections, rays_d, sigma_d, rgb_d, out);
}